// Round 4
// baseline (10805.608 us; speedup 1.0000x reference)
//
#include <hip/hip_runtime.h>
#include <hip/hip_bf16.h>
#include <math.h>

#define HDIM 256

typedef unsigned short u16;
typedef short short8 __attribute__((ext_vector_type(8)));
typedef float f32x4 __attribute__((ext_vector_type(4)));

__device__ __forceinline__ float sspf(float x) {
  float sp = (x > 0.f) ? (x + log1pf(expf(-x))) : log1pf(expf(x));
  return sp - 0.69314718055994530942f;
}
__device__ __forceinline__ float bf2f(u16 u) {
  union { unsigned int i; float f; } x; x.i = ((unsigned int)u) << 16; return x.f;
}
__device__ __forceinline__ u16 f2bf(float f) {
  union { float f; unsigned int i; } x; x.f = f;
  unsigned int r = x.i + 0x7FFFu + ((x.i >> 16) & 1u);  // RNE
  return (u16)(r >> 16);
}
__device__ __forceinline__ float4 ld4f(const float* p) { return *(const float4*)p; }
__device__ __forceinline__ float4 ld4b(const u16* p) {
  ushort4 u = *(const ushort4*)p;
  return make_float4(bf2f(u.x), bf2f(u.y), bf2f(u.z), bf2f(u.w));
}

// ---------------- MFMA GEMM: C(bf16, Mx256-strided) = act(A @ B + bias) ----------------
// 64 rows x HO cols per block (full-N tile -> in-place safe), K-tiles of 32.
// LOADER: 0 plain bf16 A; 1 ssp(len*W1+b1) on the fly;
//         2 concat(d_emb*bond_r, d_emb*bond_p) K=512;
//         3 concat(h_f32[src]*h_f32[dst], edge_attr_bf16) K=512.
// ACT: 0 none, 1 relu, 2 ssp.
struct MArgs {
  const void* A; const void* A2; const u16* Bt; const float* bias; u16* C; int M;
  const float* bondT; const int* etr; const int* etp; const int* srcI; const int* dstI;
  const float* lenp; const float* W1v; const float* b1v;
};

template<int KTOT, int HO, int LOADER, int ACT>
__global__ __launch_bounds__(256) void mgemm_k(MArgs a) {
  constexpr int NT = HO / 16;
  __shared__ u16 As[64 * 40];
  __shared__ u16 Bs[HO * 40];
  const int t = threadIdx.x;
  const int w = t >> 6;           // wave = tile-row (16 rows)
  const int lane = t & 63;
  const int m = lane & 15;        // A-row / B-col / D-col index within tile
  const int quad = lane >> 4;     // k-group for frags, row-group for D
  const int row0 = blockIdx.x * 64;
  const int r_ = t >> 2, ch = t & 3;   // staging: 4 threads per row, 8 bf16 each
  const int arow = row0 + r_;

  f32x4 acc[NT];
#pragma unroll
  for (int tn = 0; tn < NT; ++tn) { acc[tn][0] = 0.f; acc[tn][1] = 0.f; acc[tn][2] = 0.f; acc[tn][3] = 0.f; }

  for (int kb = 0; kb < KTOT; kb += 32) {
    // ---- stage A tile: 64 rows x 32 k (bf16), LDS stride 40 ----
    {
      int kk = kb + ch * 8;
      u16* dp = &As[r_ * 40 + ch * 8];
      if (LOADER == 0) {
        *(short8*)dp = *(const short8*)((const u16*)a.A + (size_t)arow * HDIM + kk);
      } else if (LOADER == 1) {
        float ln = a.lenp[arow];
        const float* wp = a.W1v + kk; const float* bp = a.b1v + kk;
        float4 w0 = ld4f(wp), w1 = ld4f(wp + 4);
        float4 c0 = ld4f(bp), c1 = ld4f(bp + 4);
        ushort4 o0, o1;
        o0.x = f2bf(sspf(ln * w0.x + c0.x)); o0.y = f2bf(sspf(ln * w0.y + c0.y));
        o0.z = f2bf(sspf(ln * w0.z + c0.z)); o0.w = f2bf(sspf(ln * w0.w + c0.w));
        o1.x = f2bf(sspf(ln * w1.x + c1.x)); o1.y = f2bf(sspf(ln * w1.y + c1.y));
        o1.z = f2bf(sspf(ln * w1.z + c1.z)); o1.w = f2bf(sspf(ln * w1.w + c1.w));
        *(ushort4*)dp = o0; *(ushort4*)(dp + 4) = o1;
      } else if (LOADER == 2) {
        int k2 = kk & 255;
        int et = (kk < 256) ? a.etr[arow] : a.etp[arow];
        const u16* ap = (const u16*)a.A + (size_t)arow * HDIM + k2;
        const float* bp = a.bondT + (size_t)et * HDIM + k2;
        float4 d0 = ld4b(ap), d1 = ld4b(ap + 4);
        float4 b0 = ld4f(bp), b1 = ld4f(bp + 4);
        ushort4 o0, o1;
        o0.x = f2bf(d0.x * b0.x); o0.y = f2bf(d0.y * b0.y); o0.z = f2bf(d0.z * b0.z); o0.w = f2bf(d0.w * b0.w);
        o1.x = f2bf(d1.x * b1.x); o1.y = f2bf(d1.y * b1.y); o1.z = f2bf(d1.z * b1.z); o1.w = f2bf(d1.w * b1.w);
        *(ushort4*)dp = o0; *(ushort4*)(dp + 4) = o1;
      } else if (LOADER == 3) {
        if (kk < 256) {
          int s = a.srcI[arow], d = a.dstI[arow];
          const float* xp = (const float*)a.A + (size_t)s * HDIM + kk;
          const float* yp = (const float*)a.A + (size_t)d * HDIM + kk;
          float4 x0 = ld4f(xp), x1 = ld4f(xp + 4);
          float4 y0 = ld4f(yp), y1 = ld4f(yp + 4);
          ushort4 o0, o1;
          o0.x = f2bf(x0.x * y0.x); o0.y = f2bf(x0.y * y0.y); o0.z = f2bf(x0.z * y0.z); o0.w = f2bf(x0.w * y0.w);
          o1.x = f2bf(x1.x * y1.x); o1.y = f2bf(x1.y * y1.y); o1.z = f2bf(x1.z * y1.z); o1.w = f2bf(x1.w * y1.w);
          *(ushort4*)dp = o0; *(ushort4*)(dp + 4) = o1;
        } else {
          *(short8*)dp = *(const short8*)((const u16*)a.A2 + (size_t)arow * HDIM + (kk - 256));
        }
      }
    }
    // ---- stage B tile: HO n-rows x 32 k from pre-transposed bf16 Bt[n][KTOT] ----
#pragma unroll
    for (int i = 0; i < HO / 64; ++i) {
      int idx = i * 256 + t;
      int n = idx >> 2, c2 = idx & 3;
      *(short8*)&Bs[n * 40 + c2 * 8] =
          *(const short8*)(a.Bt + (size_t)n * KTOT + kb + c2 * 8);
    }
    __syncthreads();
    // ---- MFMA: a-frag reused across NT col-tiles ----
    short8 af = *(const short8*)&As[(w * 16 + m) * 40 + quad * 8];
#pragma unroll
    for (int tn = 0; tn < NT; ++tn) {
      short8 bf = *(const short8*)&Bs[(tn * 16 + m) * 40 + quad * 8];
      acc[tn] = __builtin_amdgcn_mfma_f32_16x16x32_bf16(af, bf, acc[tn], 0, 0, 0);
    }
    __syncthreads();
  }
  // ---- epilogue: D lane mapping col=lane&15, row=quad*4+reg ----
#pragma unroll
  for (int tn = 0; tn < NT; ++tn) {
    float bv = a.bias ? a.bias[tn * 16 + m] : 0.f;
#pragma unroll
    for (int r = 0; r < 4; ++r) {
      int row = row0 + w * 16 + quad * 4 + r;
      if (row < a.M) {
        float x = acc[tn][r] + bv;
        if (ACT == 1) x = fmaxf(x, 0.f);
        else if (ACT == 2) x = sspf(x);
        a.C[(size_t)row * HDIM + tn * 16 + m] = f2bf(x);
      }
    }
  }
}

// ---------------- weight transpose+convert: W[K][N] f32 -> Bt[n][K] bf16 ----------------
struct WTDesc { const float* src; u16* dst; int K; int Nshift; };
struct WTList { WTDesc d[17]; };
__global__ __launch_bounds__(256) void wtrans_k(WTList wl) {
  WTDesc e = wl.d[blockIdx.y];
  int total = e.K << e.Nshift;
  int idx = blockIdx.x * 256 + threadIdx.x;
  if (idx >= total) return;
  int k = idx >> e.Nshift;
  int n = idx & ((1 << e.Nshift) - 1);
  e.dst[(size_t)n * e.K + k] = f2bf(e.src[idx]);
}

// ---------------- fp32 SIMT GEMM for node-side (M=N_nodes) ----------------
struct GArgs {
  const float* A; const float* B; const float* bias; float* C; int M;
};
template<int ACT, int CMODE>
__global__ __launch_bounds__(256) void gemm_f32_k(GArgs a) {
  __shared__ float As[64][36];
  __shared__ float Bsh[32][256];
  const int t = threadIdx.x;
  const int row0 = blockIdx.x * 64;
  const int tj = (t & 63) * 4;
  const int rbase = (t >> 6) * 16;
  float acc[16][4];
#pragma unroll
  for (int r = 0; r < 16; ++r) { acc[r][0] = 0.f; acc[r][1] = 0.f; acc[r][2] = 0.f; acc[r][3] = 0.f; }
  for (int kb = 0; kb < 256; kb += 32) {
#pragma unroll
    for (int i = 0; i < 8; ++i) {
      int idx = i * 256 + t;
      int kr = idx >> 6, c4 = idx & 63;
      *(float4*)&Bsh[kr][c4 * 4] = ld4f(&a.B[(size_t)(kb + kr) * 256 + c4 * 4]);
    }
#pragma unroll
    for (int i = 0; i < 2; ++i) {
      int idx = i * 256 + t;
      int r = idx >> 3, kv = idx & 7;
      int row = row0 + r;
      float4 v = make_float4(0.f, 0.f, 0.f, 0.f);
      if (row < a.M) v = ld4f(&a.A[(size_t)row * 256 + kb + kv * 4]);
      *(float4*)&As[r][kv * 4] = v;
    }
    __syncthreads();
#pragma unroll
    for (int k0 = 0; k0 < 32; k0 += 4) {
      float4 b0 = *(const float4*)&Bsh[k0 + 0][tj];
      float4 b1 = *(const float4*)&Bsh[k0 + 1][tj];
      float4 b2 = *(const float4*)&Bsh[k0 + 2][tj];
      float4 b3 = *(const float4*)&Bsh[k0 + 3][tj];
#pragma unroll
      for (int r = 0; r < 16; ++r) {
        float4 av = *(const float4*)&As[rbase + r][k0];
        acc[r][0] += av.x * b0.x; acc[r][1] += av.x * b0.y; acc[r][2] += av.x * b0.z; acc[r][3] += av.x * b0.w;
        acc[r][0] += av.y * b1.x; acc[r][1] += av.y * b1.y; acc[r][2] += av.y * b1.z; acc[r][3] += av.y * b1.w;
        acc[r][0] += av.z * b2.x; acc[r][1] += av.z * b2.y; acc[r][2] += av.z * b2.z; acc[r][3] += av.z * b2.w;
        acc[r][0] += av.w * b3.x; acc[r][1] += av.w * b3.y; acc[r][2] += av.w * b3.z; acc[r][3] += av.w * b3.w;
      }
    }
    __syncthreads();
  }
  float4 bv = make_float4(0.f, 0.f, 0.f, 0.f);
  if (a.bias) bv = ld4f(&a.bias[tj]);
#pragma unroll
  for (int r = 0; r < 16; ++r) {
    int row = row0 + rbase + r;
    if (row < a.M) {
      float x0 = acc[r][0] + bv.x, x1 = acc[r][1] + bv.y, x2 = acc[r][2] + bv.z, x3 = acc[r][3] + bv.w;
      if (ACT == 2) { x0 = sspf(x0); x1 = sspf(x1); x2 = sspf(x2); x3 = sspf(x3); }
      float* cp = a.C + (size_t)row * 256 + tj;
      if (CMODE == 1) {
        float4 old = *(const float4*)cp;
        x0 += old.x; x1 += old.y; x2 += old.z; x3 += old.w;
      }
      *(float4*)cp = make_float4(x0, x1, x2, x3);
    }
  }
}

// ---------------- small kernels ----------------
__global__ void node_embed_k(const int* atom_type, const float* r_feat, const float* p_feat,
                             const float* emb, const float* fW, float* z, int N, int F) {
  int n = blockIdx.x;
  int j = threadIdx.x;  // 128
  __shared__ float rr[32], pp[32];
  if (j < F) { rr[j] = r_feat[(size_t)n * F + j]; pp[j] = p_feat[(size_t)n * F + j]; }
  __syncthreads();
  float ar = 0.f, ap = 0.f;
  for (int f = 0; f < F; ++f) {
    float wv = fW[f * 128 + j];
    ar += rr[f] * wv;
    ap += pp[f] * wv;
  }
  int at = atom_type[n];
  z[(size_t)n * HDIM + j] = emb[at * 128 + j] + ar;
  z[(size_t)n * HDIM + 128 + j] = ap - ar;
}

__global__ void edge_geom_k(const float* pos, const int* src, const int* dst, float* len_out, int E) {
  int e = blockIdx.x * blockDim.x + threadIdx.x;
  if (e >= E) return;
  int s = src[e], d = dst[e];
  float dx = pos[s * 3 + 0] - pos[d * 3 + 0];
  float dy = pos[s * 3 + 1] - pos[d * 3 + 1];
  float dz = pos[s * 3 + 2] - pos[d * 3 + 2];
  len_out[e] = sqrtf(dx * dx + dy * dy + dz * dz + 1e-12f);
}

__global__ void zero_k(float4* p, int n4) {
  int i = blockIdx.x * 256 + threadIdx.x;
  if (i < n4) p[i] = make_float4(0.f, 0.f, 0.f, 0.f);
}

// ---------------- CSR build (edges grouped by dst) ----------------
__global__ void zero_int_k(int* p, int n) {
  int i = blockIdx.x * 256 + threadIdx.x;
  if (i < n) p[i] = 0;
}
__global__ void hist_k(const int* dst, int* cnt, int E) {
  int e = blockIdx.x * 256 + threadIdx.x;
  if (e < E) atomicAdd(&cnt[dst[e]], 1);
}
__global__ __launch_bounds__(256) void scan_k(const int* cnt, int* rowstart, int N) {
  __shared__ int part[256];
  int t = threadIdx.x;
  int chunk = (N + 255) / 256;
  int lo = t * chunk, hi = lo + chunk; if (hi > N) hi = N; if (lo > N) lo = N;
  int s = 0;
  for (int i = lo; i < hi; ++i) s += cnt[i];
  part[t] = s;
  __syncthreads();
  for (int off = 1; off < 256; off <<= 1) {
    int v = (t >= off) ? part[t - off] : 0;
    __syncthreads();
    part[t] += v;
    __syncthreads();
  }
  int run = (t == 0) ? 0 : part[t - 1];
  for (int i = lo; i < hi; ++i) { rowstart[i] = run; run += cnt[i]; }
  if (t == 255) rowstart[N] = run;
}
__global__ void fill_k(const int* src, const int* dst, const int* rowstart, int* cursor,
                       int2* epair, int E) {
  int e = blockIdx.x * 256 + threadIdx.x;
  if (e >= E) return;
  int d = dst[e];
  int p = atomicAdd(&cursor[d], 1);
  epair[rowstart[d] + p] = make_int2(src[e], e);
}

// ---------------- segment-sum gather: agg[n] = sum_{e in seg(n)} hh[src(e)] * Wf[e] ----------------
__global__ __launch_bounds__(256) void gather_k(const float* hh, const u16* Wf,
                                                const int2* epair, const int* rowstart,
                                                float* agg, int N) {
  int n = blockIdx.x;
  int j = threadIdx.x;   // channel
  int s0 = rowstart[n], s1 = rowstart[n + 1];
  float acc = 0.f;
  for (int i = s0; i < s1; ++i) {
    int2 ep = epair[i];
    acc += hh[(size_t)ep.x * HDIM + j] * bf2f(Wf[(size_t)ep.y * HDIM + j]);
  }
  agg[(size_t)n * HDIM + j] = acc;
}

__global__ void grad3_k(const u16* g2, const float* W3, const float* b3, float* out, int E) {
  int e = blockIdx.x * blockDim.x + threadIdx.x;
  if (e >= E) return;
  const u16* row = g2 + (size_t)e * HDIM;  // first 128 cols valid
  float s = 0.f;
#pragma unroll 8
  for (int i = 0; i < 32; ++i) {
    float4 v = ld4b(row + i * 4);
    float4 w = ld4f(W3 + i * 4);
    s += v.x * w.x + v.y * w.y + v.z * w.z + v.w * w.w;
  }
  out[e] = s + b3[0];
}

extern "C" void kernel_launch(void* const* d_in, const int* in_sizes, int n_in,
                              void* d_out, int out_size, void* d_ws, size_t ws_size,
                              hipStream_t stream) {
  const int* atom_type = (const int*)d_in[0];
  const float* r_feat  = (const float*)d_in[1];
  const float* p_feat  = (const float*)d_in[2];
  const float* pos     = (const float*)d_in[3];
  const int* eidx      = (const int*)d_in[4];
  const int* etype_r   = (const int*)d_in[5];
  const int* etype_p   = (const int*)d_in[6];
  const float* atom_emb = (const float*)d_in[7];
  const float* feat_W   = (const float*)d_in[8];
  const float* bondT    = (const float*)d_in[9];
  const float* e_W1     = (const float*)d_in[10];
  const float* e_b1     = (const float*)d_in[11];
  const float* e_W2     = (const float*)d_in[12];
  const float* e_b2     = (const float*)d_in[13];
  const float* cat_W1   = (const float*)d_in[14];
  const float* cat_b1   = (const float*)d_in[15];
  const float* cat_W2   = (const float*)d_in[16];
  const float* cat_b2   = (const float*)d_in[17];
  const float* filt_W1  = (const float*)d_in[18];
  const float* filt_b1  = (const float*)d_in[19];
  const float* filt_W2  = (const float*)d_in[20];
  const float* filt_b2  = (const float*)d_in[21];
  const float* lin1_W   = (const float*)d_in[22];
  const float* lin2_W   = (const float*)d_in[23];
  const float* lin2_b   = (const float*)d_in[24];
  const float* lin3_W   = (const float*)d_in[25];
  const float* lin3_b   = (const float*)d_in[26];
  const float* grad_W1  = (const float*)d_in[27];
  const float* grad_b1  = (const float*)d_in[28];
  const float* grad_W2  = (const float*)d_in[29];
  const float* grad_b2  = (const float*)d_in[30];
  const float* grad_W3  = (const float*)d_in[31];
  const float* grad_b3  = (const float*)d_in[32];

  const int N = in_sizes[0];
  const int F = in_sizes[1] / N;
  const int E = in_sizes[4] / 2;
  const int L = in_sizes[18] / (HDIM * HDIM);
  const int* srcI = eidx;
  const int* dstI = eidx + E;
  float* out = (float*)d_out;

  const size_t BT_ELEMS = (size_t)(14 * 256 * 256 + 2 * 512 * 256 + 256 * 128);
  const size_t CSR_INTS = (size_t)(3 * N + 1 + 2 * E + 2);  // cnt, cursor, rowstart, epair
  size_t need = 2 * (size_t)E * HDIM * 2 + 3 * (size_t)N * HDIM * 4 + BT_ELEMS * 2 + CSR_INTS * 4 + 16;
  if (ws_size < need) {
    int n4 = (out_size + 3) / 4;
    zero_k<<<(n4 + 255) / 256, 256, 0, stream>>>((float4*)d_out, n4);
    return;
  }
  char* base = (char*)d_ws;
  u16* eA = (u16*)base; base += (size_t)E * HDIM * 2;   // edge_attr (persistent)
  u16* eB = (u16*)base; base += (size_t)E * HDIM * 2;   // scratch edge buffer
  float* h   = (float*)base; base += (size_t)N * HDIM * 4;
  float* hh  = (float*)base; base += (size_t)N * HDIM * 4;
  float* agg = (float*)base; base += (size_t)N * HDIM * 4;
  u16* bt = (u16*)base; base += BT_ELEMS * 2;
  int2* epair = (int2*)base; base += (size_t)E * 8;
  int* cnt = (int*)base; base += (size_t)N * 4;
  int* cursor = (int*)base; base += (size_t)N * 4;
  int* rowstart = (int*)base; base += ((size_t)N + 1) * 4;

  // carve Bt offsets
  size_t off = 0;
  u16* bt_eW2  = bt + off; off += 256 * 256;
  u16* bt_cat1 = bt + off; off += 512 * 256;
  u16* bt_cat2 = bt + off; off += 256 * 256;
  u16* bt_f1[6]; u16* bt_f2[6];
  for (int l = 0; l < 6; ++l) { bt_f1[l] = bt + off; off += 256 * 256; }
  for (int l = 0; l < 6; ++l) { bt_f2[l] = bt + off; off += 256 * 256; }
  u16* bt_g1 = bt + off; off += 512 * 256;
  u16* bt_g2 = bt + off; off += 256 * 128;

  WTList wl;
  int wi = 0;
  wl.d[wi++] = WTDesc{e_W2, bt_eW2, 256, 8};
  wl.d[wi++] = WTDesc{cat_W1, bt_cat1, 512, 8};
  wl.d[wi++] = WTDesc{cat_W2, bt_cat2, 256, 8};
  for (int l = 0; l < 6; ++l) wl.d[wi++] = WTDesc{filt_W1 + (size_t)l * 65536, bt_f1[l], 256, 8};
  for (int l = 0; l < 6; ++l) wl.d[wi++] = WTDesc{filt_W2 + (size_t)l * 65536, bt_f2[l], 256, 8};
  wl.d[wi++] = WTDesc{grad_W1, bt_g1, 512, 8};
  wl.d[wi++] = WTDesc{grad_W2, bt_g2, 256, 7};
  wtrans_k<<<dim3(512, 17), 256, 0, stream>>>(wl);

  const int EB = E / 64;
  const int NBK = (N + 63) / 64;
  const int EBLK = (E + 255) / 256;

  // CSR build
  zero_int_k<<<(2 * N + 255) / 256, 256, 0, stream>>>(cnt, 2 * N);  // cnt+cursor contiguous
  hist_k<<<EBLK, 256, 0, stream>>>(dstI, cnt, E);
  scan_k<<<1, 256, 0, stream>>>(cnt, rowstart, N);
  fill_k<<<EBLK, 256, 0, stream>>>(srcI, dstI, rowstart, cursor, epair, E);

  node_embed_k<<<N, 128, 0, stream>>>(atom_type, r_feat, p_feat, atom_emb, feat_W, h, N, F);
  edge_geom_k<<<EBLK, 256, 0, stream>>>(pos, srcI, dstI, out + E, E);

  MArgs g;
  // d_emb = ssp(len@W1+b1) @ e_W2 + e_b2 -> eB (fused loader 1)
  g = MArgs{}; g.Bt = bt_eW2; g.bias = e_b2; g.C = eB; g.M = E;
  g.lenp = out + E; g.W1v = e_W1; g.b1v = e_b1;
  mgemm_k<256, 256, 1, 0><<<EB, 256, 0, stream>>>(g);
  // cat1: relu(concat(d_emb*bond_r, d_emb*bond_p) @ cat_W1 + cat_b1) -> eB (in place)
  g = MArgs{}; g.A = eB; g.Bt = bt_cat1; g.bias = cat_b1; g.C = eB; g.M = E;
  g.bondT = bondT; g.etr = etype_r; g.etp = etype_p;
  mgemm_k<512, 256, 2, 1><<<EB, 256, 0, stream>>>(g);
  // cat2: edge_attr = x @ cat_W2 + cat_b2 -> eA
  g = MArgs{}; g.A = eB; g.Bt = bt_cat2; g.bias = cat_b2; g.C = eA; g.M = E;
  mgemm_k<256, 256, 0, 0><<<EB, 256, 0, stream>>>(g);

  for (int l = 0; l < L; ++l) {
    const size_t bo = (size_t)l * HDIM;
    // filt1: ssp(edge_attr @ fW1 + fb1) -> eB
    g = MArgs{}; g.A = eA; g.Bt = bt_f1[l]; g.bias = filt_b1 + bo; g.C = eB; g.M = E;
    mgemm_k<256, 256, 0, 2><<<EB, 256, 0, stream>>>(g);
    // filt2: Wf = x @ fW2 + fb2 -> eB (in place)
    g = MArgs{}; g.A = eB; g.Bt = bt_f2[l]; g.bias = filt_b2 + bo; g.C = eB; g.M = E;
    mgemm_k<256, 256, 0, 0><<<EB, 256, 0, stream>>>(g);
    // lin1: hh = h @ l1 (fp32)
    GArgs ng;
    ng = GArgs{}; ng.A = h; ng.B = lin1_W + (size_t)l * 65536; ng.bias = nullptr; ng.C = hh; ng.M = N;
    gemm_f32_k<0, 0><<<NBK, 256, 0, stream>>>(ng);
    // agg[n] = sum over CSR segment (no atomics)
    gather_k<<<N, 256, 0, stream>>>(hh, eB, epair, rowstart, agg, N);
    // lin2: hh = ssp(agg @ l2 + l2b)
    ng = GArgs{}; ng.A = agg; ng.B = lin2_W + (size_t)l * 65536; ng.bias = lin2_b + bo; ng.C = hh; ng.M = N;
    gemm_f32_k<2, 0><<<NBK, 256, 0, stream>>>(ng);
    // lin3: h += hh @ l3 + l3b
    ng = GArgs{}; ng.A = hh; ng.B = lin3_W + (size_t)l * 65536; ng.bias = lin3_b + bo; ng.C = h; ng.M = N;
    gemm_f32_k<0, 1><<<NBK, 256, 0, stream>>>(ng);
  }

  // grad1: relu(concat(h[src]*h[dst], edge_attr) @ grad_W1 + grad_b1) -> eB
  g = MArgs{}; g.A = h; g.A2 = eA; g.Bt = bt_g1; g.bias = grad_b1; g.C = eB; g.M = E;
  g.srcI = srcI; g.dstI = dstI;
  mgemm_k<512, 256, 3, 1><<<EB, 256, 0, stream>>>(g);
  // grad2: relu(x @ grad_W2 + grad_b2) -> eB cols 0..127 (in place)
  g = MArgs{}; g.A = eB; g.Bt = bt_g2; g.bias = grad_b2; g.C = eB; g.M = E;
  mgemm_k<256, 128, 0, 1><<<EB, 256, 0, stream>>>(g);
  // grad3: edge_inv -> out[0:E]
  grad3_k<<<EBLK, 256, 0, stream>>>(eB, grad_W3, grad_b3, out, E);
}

// Round 5
// 6426.905 us; speedup vs baseline: 1.6813x; 1.6813x over previous
//
#include <hip/hip_runtime.h>
#include <hip/hip_bf16.h>
#include <math.h>

#define HDIM 256
#define ISTRIDE 264   // inter-tile LDS stride in u16 (264*2B=528B; word stride 132 -> m*4%32 banks, 2-way max)

typedef unsigned short u16;
typedef short short8 __attribute__((ext_vector_type(8)));
typedef float f32x4 __attribute__((ext_vector_type(4)));

__device__ __forceinline__ float sspf(float x) {
  float sp = (x > 0.f) ? (x + log1pf(expf(-x))) : log1pf(expf(x));
  return sp - 0.69314718055994530942f;
}
__device__ __forceinline__ float bf2f(u16 u) {
  union { unsigned int i; float f; } x; x.i = ((unsigned int)u) << 16; return x.f;
}
__device__ __forceinline__ u16 f2bf(float f) {
  union { float f; unsigned int i; } x; x.f = f;
  unsigned int r = x.i + 0x7FFFu + ((x.i >> 16) & 1u);  // RNE
  return (u16)(r >> 16);
}
__device__ __forceinline__ float4 ld4f(const float* p) { return *(const float4*)p; }
__device__ __forceinline__ float4 ld4b(const u16* p) {
  ushort4 u = *(const ushort4*)p;
  return make_float4(bf2f(u.x), bf2f(u.y), bf2f(u.z), bf2f(u.w));
}

// store C-frags (NT col-tiles) to inter-LDS as bf16 row-major [64][ISTRIDE], with bias+act.
// ACT: 0 none, 1 relu, 2 ssp
template<int NT, int ACT>
__device__ __forceinline__ void store_inter(u16* inter, int w, int quad, int m,
                                            const f32x4* acc, const float* bias) {
#pragma unroll
  for (int tn = 0; tn < NT; ++tn) {
    float bv = bias[tn * 16 + m];
#pragma unroll
    for (int r = 0; r < 4; ++r) {
      float x = acc[tn][r] + bv;
      if (ACT == 1) x = fmaxf(x, 0.f);
      else if (ACT == 2) x = sspf(x);
      inter[(w * 16 + quad * 4 + r) * ISTRIDE + tn * 16 + m] = f2bf(x);
    }
  }
}

// ================= fused edge encoder: len -> d_emb -> cat1 -> cat2 -> eA =================
struct EncArgs {
  const int* se_e; const float* lenp; const float* W1; const float* b1;
  const u16* btA; const float* bA;     // e_W2^T (bf16 [n][256]), e_b2
  const float* bondT; const int* etr; const int* etp;
  const u16* btB; const float* bB;     // cat_W1^T ([n][512]), cat_b1
  const u16* btC; const float* bC;     // cat_W2^T ([n][256]), cat_b2
  u16* outp;
};
__global__ __launch_bounds__(256) void encoder_k(EncArgs a) {
  __shared__ u16 inter[64 * ISTRIDE];
  const int t = threadIdx.x;
  const int w = t >> 6, lane = t & 63, m = lane & 15, quad = lane >> 4;
  const int row0 = blockIdx.x * 64;
  const int myrow = row0 + w * 16 + m;
  const int eorig = a.se_e[myrow];
  const float len = a.lenp[eorig];
  const int br = a.etr[eorig], bp = a.etp[eorig];

  f32x4 acc[16];
#pragma unroll
  for (int i = 0; i < 16; ++i) { acc[i][0]=0.f; acc[i][1]=0.f; acc[i][2]=0.f; acc[i][3]=0.f; }
  // ---- phase A: d_emb = ssp(len*W1+b1) @ e_W2   (A computed in-register) ----
  for (int kb = 0; kb < 256; kb += 32) {
    int kq = kb + quad * 8;
    float4 w0 = ld4f(a.W1 + kq), w1 = ld4f(a.W1 + kq + 4);
    float4 c0 = ld4f(a.b1 + kq), c1 = ld4f(a.b1 + kq + 4);
    short8 af;
    af[0] = (short)f2bf(sspf(len * w0.x + c0.x));
    af[1] = (short)f2bf(sspf(len * w0.y + c0.y));
    af[2] = (short)f2bf(sspf(len * w0.z + c0.z));
    af[3] = (short)f2bf(sspf(len * w0.w + c0.w));
    af[4] = (short)f2bf(sspf(len * w1.x + c1.x));
    af[5] = (short)f2bf(sspf(len * w1.y + c1.y));
    af[6] = (short)f2bf(sspf(len * w1.z + c1.z));
    af[7] = (short)f2bf(sspf(len * w1.w + c1.w));
#pragma unroll
    for (int tn = 0; tn < 16; ++tn) {
      short8 bf = *(const short8*)(a.btA + (size_t)(tn * 16 + m) * 256 + kq);
      acc[tn] = __builtin_amdgcn_mfma_f32_16x16x32_bf16(af, bf, acc[tn], 0, 0, 0);
    }
  }
  store_inter<16, 0>(inter, w, quad, m, acc, a.bA);
  __syncthreads();
  // ---- phase B: cat1, K=512: A = concat(d_emb*bond_r, d_emb*bond_p) ----
#pragma unroll
  for (int i = 0; i < 16; ++i) { acc[i][0]=0.f; acc[i][1]=0.f; acc[i][2]=0.f; acc[i][3]=0.f; }
  for (int kb = 0; kb < 512; kb += 32) {
    int kq = (kb & 255) + quad * 8;
    const float* brow = a.bondT + (size_t)((kb < 256) ? br : bp) * 256 + kq;
    short8 dv = *(const short8*)&inter[(w * 16 + m) * ISTRIDE + kq];
    float4 q0 = ld4f(brow), q1 = ld4f(brow + 4);
    short8 af;
    af[0] = (short)f2bf(bf2f((u16)dv[0]) * q0.x);
    af[1] = (short)f2bf(bf2f((u16)dv[1]) * q0.y);
    af[2] = (short)f2bf(bf2f((u16)dv[2]) * q0.z);
    af[3] = (short)f2bf(bf2f((u16)dv[3]) * q0.w);
    af[4] = (short)f2bf(bf2f((u16)dv[4]) * q1.x);
    af[5] = (short)f2bf(bf2f((u16)dv[5]) * q1.y);
    af[6] = (short)f2bf(bf2f((u16)dv[6]) * q1.z);
    af[7] = (short)f2bf(bf2f((u16)dv[7]) * q1.w);
#pragma unroll
    for (int tn = 0; tn < 16; ++tn) {
      short8 bf = *(const short8*)(a.btB + (size_t)(tn * 16 + m) * 512 + kb + quad * 8);
      acc[tn] = __builtin_amdgcn_mfma_f32_16x16x32_bf16(af, bf, acc[tn], 0, 0, 0);
    }
  }
  __syncthreads();
  store_inter<16, 1>(inter, w, quad, m, acc, a.bB);
  __syncthreads();
  // ---- phase C: cat2, K=256 ----
#pragma unroll
  for (int i = 0; i < 16; ++i) { acc[i][0]=0.f; acc[i][1]=0.f; acc[i][2]=0.f; acc[i][3]=0.f; }
  for (int kb = 0; kb < 256; kb += 32) {
    int kq = kb + quad * 8;
    short8 af = *(const short8*)&inter[(w * 16 + m) * ISTRIDE + kq];
#pragma unroll
    for (int tn = 0; tn < 16; ++tn) {
      short8 bf = *(const short8*)(a.btC + (size_t)(tn * 16 + m) * 256 + kq);
      acc[tn] = __builtin_amdgcn_mfma_f32_16x16x32_bf16(af, bf, acc[tn], 0, 0, 0);
    }
  }
#pragma unroll
  for (int tn = 0; tn < 16; ++tn) {
    float bv = a.bC[tn * 16 + m];
#pragma unroll
    for (int r = 0; r < 4; ++r)
      a.outp[(size_t)(row0 + w * 16 + quad * 4 + r) * HDIM + tn * 16 + m] = f2bf(acc[tn][r] + bv);
  }
}

// ================= fused filter net: Wf = ssp(eA@W1+b1)@W2+b2 =================
struct FiltArgs { const u16* inA; const u16* bt1; const float* b1; const u16* bt2; const float* b2; u16* outp; };
__global__ __launch_bounds__(256) void filt_k(FiltArgs a) {
  __shared__ u16 inter[64 * ISTRIDE];
  const int t = threadIdx.x;
  const int w = t >> 6, lane = t & 63, m = lane & 15, quad = lane >> 4;
  const int row0 = blockIdx.x * 64;
  const u16* arow = a.inA + (size_t)(row0 + w * 16 + m) * HDIM;
  f32x4 acc[16];
#pragma unroll
  for (int i = 0; i < 16; ++i) { acc[i][0]=0.f; acc[i][1]=0.f; acc[i][2]=0.f; acc[i][3]=0.f; }
  for (int kb = 0; kb < 256; kb += 32) {
    int kq = kb + quad * 8;
    short8 af = *(const short8*)(arow + kq);
#pragma unroll
    for (int tn = 0; tn < 16; ++tn) {
      short8 bf = *(const short8*)(a.bt1 + (size_t)(tn * 16 + m) * 256 + kq);
      acc[tn] = __builtin_amdgcn_mfma_f32_16x16x32_bf16(af, bf, acc[tn], 0, 0, 0);
    }
  }
  store_inter<16, 2>(inter, w, quad, m, acc, a.b1);
  __syncthreads();
#pragma unroll
  for (int i = 0; i < 16; ++i) { acc[i][0]=0.f; acc[i][1]=0.f; acc[i][2]=0.f; acc[i][3]=0.f; }
  for (int kb = 0; kb < 256; kb += 32) {
    int kq = kb + quad * 8;
    short8 af = *(const short8*)&inter[(w * 16 + m) * ISTRIDE + kq];
#pragma unroll
    for (int tn = 0; tn < 16; ++tn) {
      short8 bf = *(const short8*)(a.bt2 + (size_t)(tn * 16 + m) * 256 + kq);
      acc[tn] = __builtin_amdgcn_mfma_f32_16x16x32_bf16(af, bf, acc[tn], 0, 0, 0);
    }
  }
#pragma unroll
  for (int tn = 0; tn < 16; ++tn) {
    float bv = a.b2[tn * 16 + m];
#pragma unroll
    for (int r = 0; r < 4; ++r)
      a.outp[(size_t)(row0 + w * 16 + quad * 4 + r) * HDIM + tn * 16 + m] = f2bf(acc[tn][r] + bv);
  }
}

// ================= fused grad head: out = relu(relu([h_s*h_d, eA]@W1+b1)@W2+b2)@W3+b3 =================
struct GradArgs {
  const float* h; const int* se_src; const int* se_dst; const int* se_e;
  const u16* eA; const u16* bt1; const float* b1; const u16* bt2; const float* b2;
  const float* W3; const float* b3; float* outp;
};
__global__ __launch_bounds__(256) void gradf_k(GradArgs a) {
  __shared__ u16 inter[64 * ISTRIDE];
  const int t = threadIdx.x;
  const int w = t >> 6, lane = t & 63, m = lane & 15, quad = lane >> 4;
  const int row0 = blockIdx.x * 64;
  const int myrow = row0 + w * 16 + m;
  const int s = a.se_src[myrow], d = a.se_dst[myrow];
  f32x4 acc[16];
#pragma unroll
  for (int i = 0; i < 16; ++i) { acc[i][0]=0.f; acc[i][1]=0.f; acc[i][2]=0.f; acc[i][3]=0.f; }
  for (int kb = 0; kb < 512; kb += 32) {
    int kq = kb + quad * 8;
    short8 af;
    if (kb < 256) {
      const float* xp = a.h + (size_t)s * HDIM + kq;
      const float* yp = a.h + (size_t)d * HDIM + kq;
      float4 x0 = ld4f(xp), x1 = ld4f(xp + 4);
      float4 y0 = ld4f(yp), y1 = ld4f(yp + 4);
      af[0] = (short)f2bf(x0.x * y0.x); af[1] = (short)f2bf(x0.y * y0.y);
      af[2] = (short)f2bf(x0.z * y0.z); af[3] = (short)f2bf(x0.w * y0.w);
      af[4] = (short)f2bf(x1.x * y1.x); af[5] = (short)f2bf(x1.y * y1.y);
      af[6] = (short)f2bf(x1.z * y1.z); af[7] = (short)f2bf(x1.w * y1.w);
    } else {
      af = *(const short8*)(a.eA + (size_t)myrow * HDIM + kq - 256);
    }
#pragma unroll
    for (int tn = 0; tn < 16; ++tn) {
      short8 bf = *(const short8*)(a.bt1 + (size_t)(tn * 16 + m) * 512 + kq);
      acc[tn] = __builtin_amdgcn_mfma_f32_16x16x32_bf16(af, bf, acc[tn], 0, 0, 0);
    }
  }
  store_inter<16, 1>(inter, w, quad, m, acc, a.b1);
  __syncthreads();
  f32x4 acc2[8];
#pragma unroll
  for (int i = 0; i < 8; ++i) { acc2[i][0]=0.f; acc2[i][1]=0.f; acc2[i][2]=0.f; acc2[i][3]=0.f; }
  for (int kb = 0; kb < 256; kb += 32) {
    int kq = kb + quad * 8;
    short8 af = *(const short8*)&inter[(w * 16 + m) * ISTRIDE + kq];
#pragma unroll
    for (int tn = 0; tn < 8; ++tn) {
      short8 bf = *(const short8*)(a.bt2 + (size_t)(tn * 16 + m) * 256 + kq);
      acc2[tn] = __builtin_amdgcn_mfma_f32_16x16x32_bf16(af, bf, acc2[tn], 0, 0, 0);
    }
  }
  // relu + partial dot with W3 over owned cols
  float p[4] = {0.f, 0.f, 0.f, 0.f};
#pragma unroll
  for (int tn = 0; tn < 8; ++tn) {
    float w3 = a.W3[tn * 16 + m];
    float bv = a.b2[tn * 16 + m];
#pragma unroll
    for (int r = 0; r < 4; ++r) p[r] += fmaxf(acc2[tn][r] + bv, 0.f) * w3;
  }
  __syncthreads();
  float* red = (float*)inter;   // 64 rows x 17
#pragma unroll
  for (int r = 0; r < 4; ++r) red[(w * 16 + quad * 4 + r) * 17 + m] = p[r];
  __syncthreads();
  if (t < 64) {
    float ssum = a.b3[0];
#pragma unroll
    for (int i = 0; i < 16; ++i) ssum += red[t * 17 + i];
    a.outp[a.se_e[row0 + t]] = ssum;
  }
}

// ================= weight transpose+convert: W[K][N] f32 -> Bt[n][K] bf16 =================
struct WTDesc { const float* src; u16* dst; int K; int Nshift; };
struct WTList { WTDesc d[17]; };
__global__ __launch_bounds__(256) void wtrans_k(WTList wl) {
  WTDesc e = wl.d[blockIdx.y];
  int total = e.K << e.Nshift;
  int idx = blockIdx.x * 256 + threadIdx.x;
  if (idx >= total) return;
  int k = idx >> e.Nshift;
  int n = idx & ((1 << e.Nshift) - 1);
  e.dst[(size_t)n * e.K + k] = f2bf(e.src[idx]);
}

// ================= fp32 SIMT GEMM for node-side =================
struct GArgs { const float* A; const float* B; const float* bias; float* C; int M; };
template<int ACT, int CMODE>
__global__ __launch_bounds__(256) void gemm_f32_k(GArgs a) {
  __shared__ float As[64][36];
  __shared__ float Bsh[32][256];
  const int t = threadIdx.x;
  const int row0 = blockIdx.x * 64;
  const int tj = (t & 63) * 4;
  const int rbase = (t >> 6) * 16;
  float acc[16][4];
#pragma unroll
  for (int r = 0; r < 16; ++r) { acc[r][0]=0.f; acc[r][1]=0.f; acc[r][2]=0.f; acc[r][3]=0.f; }
  for (int kb = 0; kb < 256; kb += 32) {
#pragma unroll
    for (int i = 0; i < 8; ++i) {
      int idx = i * 256 + t;
      int kr = idx >> 6, c4 = idx & 63;
      *(float4*)&Bsh[kr][c4 * 4] = ld4f(&a.B[(size_t)(kb + kr) * 256 + c4 * 4]);
    }
#pragma unroll
    for (int i = 0; i < 2; ++i) {
      int idx = i * 256 + t;
      int r = idx >> 3, kv = idx & 7;
      int row = row0 + r;
      float4 v = make_float4(0.f, 0.f, 0.f, 0.f);
      if (row < a.M) v = ld4f(&a.A[(size_t)row * 256 + kb + kv * 4]);
      *(float4*)&As[r][kv * 4] = v;
    }
    __syncthreads();
#pragma unroll
    for (int k0 = 0; k0 < 32; k0 += 4) {
      float4 b0 = *(const float4*)&Bsh[k0 + 0][tj];
      float4 b1 = *(const float4*)&Bsh[k0 + 1][tj];
      float4 b2 = *(const float4*)&Bsh[k0 + 2][tj];
      float4 b3 = *(const float4*)&Bsh[k0 + 3][tj];
#pragma unroll
      for (int r = 0; r < 16; ++r) {
        float4 av = *(const float4*)&As[rbase + r][k0];
        acc[r][0] += av.x * b0.x; acc[r][1] += av.x * b0.y; acc[r][2] += av.x * b0.z; acc[r][3] += av.x * b0.w;
        acc[r][0] += av.y * b1.x; acc[r][1] += av.y * b1.y; acc[r][2] += av.y * b1.z; acc[r][3] += av.y * b1.w;
        acc[r][0] += av.z * b2.x; acc[r][1] += av.z * b2.y; acc[r][2] += av.z * b2.z; acc[r][3] += av.z * b2.w;
        acc[r][0] += av.w * b3.x; acc[r][1] += av.w * b3.y; acc[r][2] += av.w * b3.z; acc[r][3] += av.w * b3.w;
      }
    }
    __syncthreads();
  }
  float4 bv = make_float4(0.f, 0.f, 0.f, 0.f);
  if (a.bias) bv = ld4f(&a.bias[tj]);
#pragma unroll
  for (int r = 0; r < 16; ++r) {
    int row = row0 + rbase + r;
    if (row < a.M) {
      float x0 = acc[r][0] + bv.x, x1 = acc[r][1] + bv.y, x2 = acc[r][2] + bv.z, x3 = acc[r][3] + bv.w;
      if (ACT == 2) { x0 = sspf(x0); x1 = sspf(x1); x2 = sspf(x2); x3 = sspf(x3); }
      float* cp = a.C + (size_t)row * 256 + tj;
      if (CMODE == 1) {
        float4 old = *(const float4*)cp;
        x0 += old.x; x1 += old.y; x2 += old.z; x3 += old.w;
      }
      *(float4*)cp = make_float4(x0, x1, x2, x3);
    }
  }
}

// ================= small kernels =================
__global__ void node_embed_k(const int* atom_type, const float* r_feat, const float* p_feat,
                             const float* emb, const float* fW, float* z, int N, int F) {
  int n = blockIdx.x;
  int j = threadIdx.x;  // 128
  __shared__ float rr[32], pp[32];
  if (j < F) { rr[j] = r_feat[(size_t)n * F + j]; pp[j] = p_feat[(size_t)n * F + j]; }
  __syncthreads();
  float ar = 0.f, ap = 0.f;
  for (int f = 0; f < F; ++f) {
    float wv = fW[f * 128 + j];
    ar += rr[f] * wv;
    ap += pp[f] * wv;
  }
  int at = atom_type[n];
  z[(size_t)n * HDIM + j] = emb[at * 128 + j] + ar;
  z[(size_t)n * HDIM + 128 + j] = ap - ar;
}

__global__ void edge_geom_k(const float* pos, const int* src, const int* dst, float* len_out, int E) {
  int e = blockIdx.x * blockDim.x + threadIdx.x;
  if (e >= E) return;
  int s = src[e], d = dst[e];
  float dx = pos[s * 3 + 0] - pos[d * 3 + 0];
  float dy = pos[s * 3 + 1] - pos[d * 3 + 1];
  float dz = pos[s * 3 + 2] - pos[d * 3 + 2];
  len_out[e] = sqrtf(dx * dx + dy * dy + dz * dz + 1e-12f);
}

__global__ void zero_k(float4* p, int n4) {
  int i = blockIdx.x * 256 + threadIdx.x;
  if (i < n4) p[i] = make_float4(0.f, 0.f, 0.f, 0.f);
}

// ================= CSR build (edges sorted by dst) =================
__global__ void zero_int_k(int* p, int n) {
  int i = blockIdx.x * 256 + threadIdx.x;
  if (i < n) p[i] = 0;
}
__global__ void hist_k(const int* dst, int* cnt, int E) {
  int e = blockIdx.x * 256 + threadIdx.x;
  if (e < E) atomicAdd(&cnt[dst[e]], 1);
}
__global__ __launch_bounds__(256) void scan_k(const int* cnt, int* rowstart, int N) {
  __shared__ int part[256];
  int t = threadIdx.x;
  int chunk = (N + 255) / 256;
  int lo = t * chunk, hi = lo + chunk; if (hi > N) hi = N; if (lo > N) lo = N;
  int s = 0;
  for (int i = lo; i < hi; ++i) s += cnt[i];
  part[t] = s;
  __syncthreads();
  for (int off = 1; off < 256; off <<= 1) {
    int v = (t >= off) ? part[t - off] : 0;
    __syncthreads();
    part[t] += v;
    __syncthreads();
  }
  int run = (t == 0) ? 0 : part[t - 1];
  for (int i = lo; i < hi; ++i) { rowstart[i] = run; run += cnt[i]; }
  if (t == 255) rowstart[N] = run;
}
__global__ void fill_k(const int* src, const int* dst, const int* rowstart, int* cursor,
                       int* se_src, int* se_dst, int* se_e, int E) {
  int e = blockIdx.x * 256 + threadIdx.x;
  if (e >= E) return;
  int d = dst[e];
  int p = atomicAdd(&cursor[d], 1);
  int idx = rowstart[d] + p;
  se_src[idx] = src[e];
  se_dst[idx] = d;
  se_e[idx] = e;
}

// ================= segment-sum gather (sorted Wf) =================
__global__ __launch_bounds__(256) void gather_k(const float* hh, const u16* Wf,
                                                const int* se_src, const int* rowstart,
                                                float* agg, int N) {
  int n = blockIdx.x;
  int j = threadIdx.x;
  int s0 = rowstart[n], s1 = rowstart[n + 1];
  float acc = 0.f;
  for (int i = s0; i < s1; ++i)
    acc += hh[(size_t)se_src[i] * HDIM + j] * bf2f(Wf[(size_t)i * HDIM + j]);
  agg[(size_t)n * HDIM + j] = acc;
}

extern "C" void kernel_launch(void* const* d_in, const int* in_sizes, int n_in,
                              void* d_out, int out_size, void* d_ws, size_t ws_size,
                              hipStream_t stream) {
  const int* atom_type = (const int*)d_in[0];
  const float* r_feat  = (const float*)d_in[1];
  const float* p_feat  = (const float*)d_in[2];
  const float* pos     = (const float*)d_in[3];
  const int* eidx      = (const int*)d_in[4];
  const int* etype_r   = (const int*)d_in[5];
  const int* etype_p   = (const int*)d_in[6];
  const float* atom_emb = (const float*)d_in[7];
  const float* feat_W   = (const float*)d_in[8];
  const float* bondT    = (const float*)d_in[9];
  const float* e_W1     = (const float*)d_in[10];
  const float* e_b1     = (const float*)d_in[11];
  const float* e_W2     = (const float*)d_in[12];
  const float* e_b2     = (const float*)d_in[13];
  const float* cat_W1   = (const float*)d_in[14];
  const float* cat_b1   = (const float*)d_in[15];
  const float* cat_W2   = (const float*)d_in[16];
  const float* cat_b2   = (const float*)d_in[17];
  const float* filt_W1  = (const float*)d_in[18];
  const float* filt_b1  = (const float*)d_in[19];
  const float* filt_W2  = (const float*)d_in[20];
  const float* filt_b2  = (const float*)d_in[21];
  const float* lin1_W   = (const float*)d_in[22];
  const float* lin2_W   = (const float*)d_in[23];
  const float* lin2_b   = (const float*)d_in[24];
  const float* lin3_W   = (const float*)d_in[25];
  const float* lin3_b   = (const float*)d_in[26];
  const float* grad_W1  = (const float*)d_in[27];
  const float* grad_b1  = (const float*)d_in[28];
  const float* grad_W2  = (const float*)d_in[29];
  const float* grad_b2  = (const float*)d_in[30];
  const float* grad_W3  = (const float*)d_in[31];
  const float* grad_b3  = (const float*)d_in[32];

  const int N = in_sizes[0];
  const int F = in_sizes[1] / N;
  const int E = in_sizes[4] / 2;
  const int L = in_sizes[18] / (HDIM * HDIM);
  const int* srcI = eidx;
  const int* dstI = eidx + E;
  float* out = (float*)d_out;

  const size_t BT_ELEMS = (size_t)(14 * 256 * 256 + 2 * 512 * 256 + 256 * 128);
  size_t need = 2 * (size_t)E * HDIM * 2 + 3 * (size_t)N * HDIM * 4 + BT_ELEMS * 2
              + (size_t)(3 * E + 2 * N + N + 1) * 4 + 64;
  if (ws_size < need) {
    int n4 = (out_size + 3) / 4;
    zero_k<<<(n4 + 255) / 256, 256, 0, stream>>>((float4*)d_out, n4);
    return;
  }
  char* base = (char*)d_ws;
  u16* eA = (u16*)base; base += (size_t)E * HDIM * 2;   // edge_attr (sorted order, persistent)
  u16* Wf = (u16*)base; base += (size_t)E * HDIM * 2;   // filter output (sorted order)
  float* h   = (float*)base; base += (size_t)N * HDIM * 4;
  float* hh  = (float*)base; base += (size_t)N * HDIM * 4;
  float* agg = (float*)base; base += (size_t)N * HDIM * 4;
  u16* bt = (u16*)base; base += BT_ELEMS * 2;
  int* se_src = (int*)base; base += (size_t)E * 4;
  int* se_dst = (int*)base; base += (size_t)E * 4;
  int* se_e   = (int*)base; base += (size_t)E * 4;
  int* cnt    = (int*)base; base += (size_t)N * 4;
  int* cursor = (int*)base; base += (size_t)N * 4;
  int* rowstart = (int*)base; base += ((size_t)N + 1) * 4;

  // carve Bt offsets
  size_t off = 0;
  u16* bt_eW2  = bt + off; off += 256 * 256;
  u16* bt_cat1 = bt + off; off += 512 * 256;
  u16* bt_cat2 = bt + off; off += 256 * 256;
  u16* bt_f1[6]; u16* bt_f2[6];
  for (int l = 0; l < 6; ++l) { bt_f1[l] = bt + off; off += 256 * 256; }
  for (int l = 0; l < 6; ++l) { bt_f2[l] = bt + off; off += 256 * 256; }
  u16* bt_g1 = bt + off; off += 512 * 256;
  u16* bt_g2 = bt + off; off += 256 * 128;

  WTList wl;
  int wi = 0;
  wl.d[wi++] = WTDesc{e_W2, bt_eW2, 256, 8};
  wl.d[wi++] = WTDesc{cat_W1, bt_cat1, 512, 8};
  wl.d[wi++] = WTDesc{cat_W2, bt_cat2, 256, 8};
  for (int l = 0; l < 6; ++l) wl.d[wi++] = WTDesc{filt_W1 + (size_t)l * 65536, bt_f1[l], 256, 8};
  for (int l = 0; l < 6; ++l) wl.d[wi++] = WTDesc{filt_W2 + (size_t)l * 65536, bt_f2[l], 256, 8};
  wl.d[wi++] = WTDesc{grad_W1, bt_g1, 512, 8};
  wl.d[wi++] = WTDesc{grad_W2, bt_g2, 256, 7};
  wtrans_k<<<dim3(512, 17), 256, 0, stream>>>(wl);

  const int EB = E / 64;
  const int NBK = (N + 63) / 64;
  const int EBLK = (E + 255) / 256;

  // CSR build / dst-sort
  zero_int_k<<<(2 * N + 255) / 256, 256, 0, stream>>>(cnt, 2 * N);  // cnt+cursor contiguous
  hist_k<<<EBLK, 256, 0, stream>>>(dstI, cnt, E);
  scan_k<<<1, 256, 0, stream>>>(cnt, rowstart, N);
  fill_k<<<EBLK, 256, 0, stream>>>(srcI, dstI, rowstart, cursor, se_src, se_dst, se_e, E);

  node_embed_k<<<N, 128, 0, stream>>>(atom_type, r_feat, p_feat, atom_emb, feat_W, h, N, F);
  edge_geom_k<<<EBLK, 256, 0, stream>>>(pos, srcI, dstI, out + E, E);

  // fused edge encoder -> eA (sorted order)
  EncArgs ea;
  ea.se_e = se_e; ea.lenp = out + E; ea.W1 = e_W1; ea.b1 = e_b1;
  ea.btA = bt_eW2; ea.bA = e_b2;
  ea.bondT = bondT; ea.etr = etype_r; ea.etp = etype_p;
  ea.btB = bt_cat1; ea.bB = cat_b1;
  ea.btC = bt_cat2; ea.bC = cat_b2;
  ea.outp = eA;
  encoder_k<<<EB, 256, 0, stream>>>(ea);

  for (int l = 0; l < L; ++l) {
    const size_t bo = (size_t)l * HDIM;
    FiltArgs fa{eA, bt_f1[l], filt_b1 + bo, bt_f2[l], filt_b2 + bo, Wf};
    filt_k<<<EB, 256, 0, stream>>>(fa);
    GArgs ng{h, lin1_W + (size_t)l * 65536, nullptr, hh, N};
    gemm_f32_k<0, 0><<<NBK, 256, 0, stream>>>(ng);
    gather_k<<<N, 256, 0, stream>>>(hh, Wf, se_src, rowstart, agg, N);
    GArgs n2{agg, lin2_W + (size_t)l * 65536, lin2_b + bo, hh, N};
    gemm_f32_k<2, 0><<<NBK, 256, 0, stream>>>(n2);
    GArgs n3{hh, lin3_W + (size_t)l * 65536, lin3_b + bo, h, N};
    gemm_f32_k<0, 1><<<NBK, 256, 0, stream>>>(n3);
  }

  GradArgs ga;
  ga.h = h; ga.se_src = se_src; ga.se_dst = se_dst; ga.se_e = se_e;
  ga.eA = eA; ga.bt1 = bt_g1; ga.b1 = grad_b1; ga.bt2 = bt_g2; ga.b2 = grad_b2;
  ga.W3 = grad_W3; ga.b3 = grad_b3; ga.outp = out;
  gradf_k<<<EB, 256, 0, stream>>>(ga);
}